// Round 21
// baseline (330.678 us; speedup 1.0000x reference)
//
#include <hip/hip_runtime.h>
#include <hip/hip_bf16.h>
#include <stdint.h>

// Problem constants
#define BATCH 16
#define SEQ   1024
#define HIDN  1024
#define NH    16
#define HD    64
#define PBSTRIDE 1025  // pos_bias last-dim stride (2*512+1)

#define TS  64    // attn K/V tile row stride (shorts) — linear, XOR-swizzled
#define AST 76    // P tile stride (shorts): 38 dw = 6 mod 32 -> conflict-free (r9/r10: 0 conflicts)

// K-projection pre-scale: 0.125 (1/sqrt(D)) * log2(e), folded into Wk/bk in fp32 before bf16 rounding
#define KSCL 0.18033688f
#define L2E  1.44269504f
#define MSUB 11.54156032f   // 8 * log2(e): fixed softmax shift (replaces running max)

// Raw v_exp_f32: args are in [-35,-2] (bounded scores, fixed shift) — no denorm/overflow edge cases.
#if __has_builtin(__builtin_amdgcn_exp2f)
#define EXP2(x) __builtin_amdgcn_exp2f(x)
#else
#define EXP2(x) exp2f(x)
#endif

typedef __attribute__((ext_vector_type(8))) short short8;
typedef __attribute__((ext_vector_type(4))) short short4v;
typedef __attribute__((ext_vector_type(4))) float f32x4;

__device__ __forceinline__ float bf2f(short x) {
    unsigned int u = ((unsigned int)(unsigned short)x) << 16;
    union { unsigned int u; float f; } c; c.u = u; return c.f;
}
__device__ __forceinline__ short f2bf(float f) {
    union { float f; unsigned int u; } c; c.f = f;
    unsigned int r = c.u + 0x7FFFu + ((c.u >> 16) & 1u);  // RNE
    return (short)(r >> 16);
}
// Truncation (1 op). Used ONLY for P: O = sum(P v)/sum(P) uses the same truncated P in
// numerator and denominator, so the ~0.2% downward bias cancels; residual is zero-mean noise.
__device__ __forceinline__ short f2bf_trunc(float f) {
    union { float f; unsigned int u; } c; c.f = f;
    return (short)(c.u >> 16);
}

typedef __attribute__((address_space(1))) void gvoid;
typedef __attribute__((address_space(3))) void svoid;
__device__ __forceinline__ void gload_lds16(const void* g, void* l) {
    __builtin_amdgcn_global_load_lds((gvoid*)g, (svoid*)l, 16, 0, 0);
}

// -------- weight conversion fp32 -> bf16 (all 4 weights, K slot pre-scaled) + fused bias build --------
__global__ void convwb_k(const float* __restrict__ s0, const float* __restrict__ s1,
                         const float* __restrict__ s2, const float* __restrict__ s3,
                         const float* __restrict__ b0, const float* __restrict__ b1,
                         const float* __restrict__ b2,
                         short* __restrict__ d0, short* __restrict__ d1,
                         short* __restrict__ d2, short* __restrict__ d3,
                         float* __restrict__ fbo) {
    const float* src = (blockIdx.y == 0) ? s0 : (blockIdx.y == 1) ? s1 : (blockIdx.y == 2) ? s2 : s3;
    short* dst       = (blockIdx.y == 0) ? d0 : (blockIdx.y == 1) ? d1 : (blockIdx.y == 2) ? d2 : d3;
    const float scl  = (blockIdx.y == 1) ? KSCL : 1.0f;
    int i = (blockIdx.x * 256 + threadIdx.x) * 4;
    float4 f = *(const float4*)(src + i);
    short4v o;
    o[0] = f2bf(f.x * scl); o[1] = f2bf(f.y * scl); o[2] = f2bf(f.z * scl); o[3] = f2bf(f.w * scl);
    *(short4v*)(dst + i) = o;
    // fused q/k/v bias vector [3072], bk slice pre-scaled
    if (blockIdx.y == 0 && blockIdx.x < 12) {
        int i2 = blockIdx.x * 256 + threadIdx.x;  // 0..3071
        const float* s = (i2 < 1024) ? b0 : (i2 < 2048) ? b1 : b2;
        float scl2 = (i2 >= 1024 && i2 < 2048) ? KSCL : 1.0f;
        fbo[i2] = s[i2 & 1023] * scl2;
    }
}

// -------- posemb v2: 16 elements/thread (2x short8), grid 4096 --------
__global__ void posemb_k(const float* __restrict__ hid, const float* __restrict__ wpe,
                         const float* __restrict__ bpe, short* __restrict__ hs) {
    long long idx = (long long)blockIdx.x * blockDim.x + threadIdx.x;
    long long base = idx * 16;
    int c = (int)(base & (HIDN - 1));
    int s = (int)((base >> 10) & (SEQ - 1));
    float pos = (float)(s - 512) * (1.0f / 512.0f);
#pragma unroll
    for (int half = 0; half < 2; ++half) {
        long long b8 = base + half * 8;
        int c8 = c + half * 8;
        float4 h0 = *(const float4*)(hid + b8);
        float4 h1 = *(const float4*)(hid + b8 + 4);
        float4 w0 = *(const float4*)(wpe + c8);
        float4 w1 = *(const float4*)(wpe + c8 + 4);
        float4 p0 = *(const float4*)(bpe + c8);
        float4 p1 = *(const float4*)(bpe + c8 + 4);
        short8 ov;
        ov[0] = f2bf(h0.x + pos * w0.x + p0.x);
        ov[1] = f2bf(h0.y + pos * w0.y + p0.y);
        ov[2] = f2bf(h0.z + pos * w0.z + p0.z);
        ov[3] = f2bf(h0.w + pos * w0.w + p0.w);
        ov[4] = f2bf(h1.x + pos * w1.x + p1.x);
        ov[5] = f2bf(h1.y + pos * w1.y + p1.y);
        ov[6] = f2bf(h1.z + pos * w1.z + p1.z);
        ov[7] = f2bf(h1.w + pos * w1.w + p1.w);
        *(short8*)(hs + b8) = ov;
    }
}

// -------- fused QKV GEMM v3 (r16/r18-verified): BK=64 + swizzle + XCD remap + dbuf pipeline --------
// flat grid 3072: xcd=d&7, tx=(d>>3)/16 (0..23), ty=xcd*16+((d>>3)&15).
// which = tn>>10: 0->q [B,H,S,D], 1->k [B,H,S,D], 2->v^T [B,H,D,S]
__global__ __launch_bounds__(256) void gemm_qkv(const short* __restrict__ A,
                                                const short* __restrict__ W,
                                                const float* __restrict__ fb,
                                                short* __restrict__ q,
                                                short* __restrict__ k,
                                                short* __restrict__ vt) {
    __shared__ __align__(16) short Als[2][128 * 64];
    __shared__ __align__(16) short Bls[2][128 * 64];
    const int tid  = threadIdx.x;
    const int lane = tid & 63;
    const int w    = tid >> 6;
    const int wr   = w >> 1, wc = w & 1;
    const int d0   = blockIdx.x;
    const int xcd  = d0 & 7;
    const int idx  = d0 >> 3;            // 0..383
    const int tx   = idx >> 4;           // 0..23
    const int ty   = xcd * 16 + (idx & 15);
    const int tm   = ty * 128;
    const int tn   = tx * 128;

    f32x4 acc[4][4] = {};

    const int srow = w * 32 + (lane >> 3);
    const int scol = ((lane & 7) ^ (lane >> 3)) * 8;
    const long long a_base = (long long)(tm + srow) * 1024 + scol;
    const long long b_base = (long long)(tn + srow) * 1024 + scol;
    const int ldsw = w * 4096;           // bytes within buffer

    const int fr  = lane & 15;
    const int fg8 = (lane >> 4) * 8;
    const int frx = (lane & 7) * 8;      // read-side XOR (shorts)

#pragma unroll
    for (int c = 0; c < 4; ++c) {
        gload_lds16((const void*)(A + a_base + (long long)c * 8 * 1024), (char*)Als[0] + ldsw + c * 1024);
        gload_lds16((const void*)(W + b_base + (long long)c * 8 * 1024), (char*)Bls[0] + ldsw + c * 1024);
    }
    asm volatile("s_waitcnt vmcnt(0)" ::: "memory");
    __syncthreads();

    int cur = 0;
    for (int k0 = 0; k0 < 1024; k0 += 64) {
        if (k0 + 64 < 1024) {
            const int nb = cur ^ 1;
#pragma unroll
            for (int c = 0; c < 4; ++c) {
                gload_lds16((const void*)(A + a_base + (long long)c * 8 * 1024 + k0 + 64),
                            (char*)Als[nb] + ldsw + c * 1024);
                gload_lds16((const void*)(W + b_base + (long long)c * 8 * 1024 + k0 + 64),
                            (char*)Bls[nb] + ldsw + c * 1024);
            }
        }
#pragma unroll
        for (int ks = 0; ks < 2; ++ks) {
            short8 af[4], bfr[4];
#pragma unroll
            for (int r = 0; r < 4; ++r) {
                af[r]  = *(const short8*)(Als[cur] + (wr * 64 + r * 16 + fr) * 64 + ((ks * 32 + fg8) ^ frx));
                bfr[r] = *(const short8*)(Bls[cur] + (wc * 64 + r * 16 + fr) * 64 + ((ks * 32 + fg8) ^ frx));
            }
#pragma unroll
            for (int mi = 0; mi < 4; ++mi)
#pragma unroll
                for (int ni = 0; ni < 4; ++ni)
                    acc[mi][ni] = __builtin_amdgcn_mfma_f32_16x16x32_bf16(af[mi], bfr[ni], acc[mi][ni], 0, 0, 0);
        }
        __syncthreads();
        cur ^= 1;
    }

    const int which = tn >> 10;  // block-uniform
    const int g4 = (lane >> 4) * 4;
    if (which < 2) {
        short* dst = (which == 0) ? q : k;
#pragma unroll
        for (int ni = 0; ni < 4; ++ni) {
            int col = tn + wc * 64 + ni * 16 + fr;
            int cc  = col & 1023;
            int h   = cc >> 6, d = cc & 63;
            float bv = fb[col];
#pragma unroll
            for (int mi = 0; mi < 4; ++mi) {
#pragma unroll
                for (int r = 0; r < 4; ++r) {
                    int row = tm + wr * 64 + mi * 16 + g4 + r;
                    int b = row >> 10, s = row & 1023;
                    dst[(((long long)(b * NH + h) * SEQ + s) << 6) + d] = f2bf(acc[mi][ni][r] + bv);
                }
            }
        }
    } else {
        // v^T: rows (s) consecutive over r -> vectorized short4 stores (r15-verified)
#pragma unroll
        for (int ni = 0; ni < 4; ++ni) {
            int col = tn + wc * 64 + ni * 16 + fr;
            int cc  = col & 1023;
            int h   = cc >> 6, d = cc & 63;
            float bv = fb[col];
#pragma unroll
            for (int mi = 0; mi < 4; ++mi) {
                int row0 = tm + wr * 64 + mi * 16 + g4;
                int b = row0 >> 10, s0 = row0 & 1023;
                short4v o4;
#pragma unroll
                for (int r = 0; r < 4; ++r) o4[r] = f2bf(acc[mi][ni][r] + bv);
                *(short4v*)(vt + ((long long)(b * NH + h) * HD + d) * SEQ + s0) = o4;
            }
        }
    }
}

// -------- out-proj GEMM v3 (r15-verified): BK=64 + swizzle + XCD remap + dbuf; fp32 out --------
__global__ __launch_bounds__(256) void gemm_out(const short* __restrict__ A,
                                                const short* __restrict__ W,
                                                const float* __restrict__ bias,
                                                float* __restrict__ Cout) {
    __shared__ __align__(16) short Als[2][128 * 64];
    __shared__ __align__(16) short Bls[2][128 * 64];
    const int tid  = threadIdx.x;
    const int lane = tid & 63;
    const int w    = tid >> 6;
    const int wr   = w >> 1, wc = w & 1;
    const int d0   = blockIdx.x;
    const int xcd  = d0 & 7;
    const int idx  = d0 >> 3;            // 0..127
    const int tx   = idx >> 4;           // 0..7
    const int ty   = xcd * 16 + (idx & 15);
    const int tm   = ty * 128;
    const int tn   = tx * 128;

    f32x4 acc[4][4] = {};

    const int srow = w * 32 + (lane >> 3);
    const int scol = ((lane & 7) ^ (lane >> 3)) * 8;
    const long long a_base = (long long)(tm + srow) * 1024 + scol;
    const long long b_base = (long long)(tn + srow) * 1024 + scol;
    const int ldsw = w * 4096;

    const int fr  = lane & 15;
    const int fg8 = (lane >> 4) * 8;
    const int frx = (lane & 7) * 8;

#pragma unroll
    for (int c = 0; c < 4; ++c) {
        gload_lds16((const void*)(A + a_base + (long long)c * 8 * 1024), (char*)Als[0] + ldsw + c * 1024);
        gload_lds16((const void*)(W + b_base + (long long)c * 8 * 1024), (char*)Bls[0] + ldsw + c * 1024);
    }
    asm volatile("s_waitcnt vmcnt(0)" ::: "memory");
    __syncthreads();

    int cur = 0;
    for (int k0 = 0; k0 < 1024; k0 += 64) {
        if (k0 + 64 < 1024) {
            const int nb = cur ^ 1;
#pragma unroll
            for (int c = 0; c < 4; ++c) {
                gload_lds16((const void*)(A + a_base + (long long)c * 8 * 1024 + k0 + 64),
                            (char*)Als[nb] + ldsw + c * 1024);
                gload_lds16((const void*)(W + b_base + (long long)c * 8 * 1024 + k0 + 64),
                            (char*)Bls[nb] + ldsw + c * 1024);
            }
        }
#pragma unroll
        for (int ks = 0; ks < 2; ++ks) {
            short8 af[4], bfr[4];
#pragma unroll
            for (int r = 0; r < 4; ++r) {
                af[r]  = *(const short8*)(Als[cur] + (wr * 64 + r * 16 + fr) * 64 + ((ks * 32 + fg8) ^ frx));
                bfr[r] = *(const short8*)(Bls[cur] + (wc * 64 + r * 16 + fr) * 64 + ((ks * 32 + fg8) ^ frx));
            }
#pragma unroll
            for (int mi = 0; mi < 4; ++mi)
#pragma unroll
                for (int ni = 0; ni < 4; ++ni)
                    acc[mi][ni] = __builtin_amdgcn_mfma_f32_16x16x32_bf16(af[mi], bfr[ni], acc[mi][ni], 0, 0, 0);
        }
        __syncthreads();
        cur ^= 1;
    }

    const int g4 = (lane >> 4) * 4;
#pragma unroll
    for (int ni = 0; ni < 4; ++ni) {
        int col = tn + wc * 64 + ni * 16 + fr;
        float bv = bias[col];
#pragma unroll
        for (int mi = 0; mi < 4; ++mi)
#pragma unroll
            for (int r = 0; r < 4; ++r) {
                int row = tm + wr * 64 + mi * 16 + g4 + r;
                Cout[(long long)row * 1024 + col] = acc[mi][ni][r] + bv;
            }
    }
}

// -------- attention v11 (r16-verified): 8-wave, dbuf gload_lds, XCD remap, C-init bias, trunc P --------
// grid 1024: xcd=d&7, idx=d>>3; bh=xcd*32+(idx>>2), qt=idx&3 (bh XCD-affine, bijective).
__global__ __launch_bounds__(512) void attn_k(const short* __restrict__ Q,
                                              const short* __restrict__ Kg,
                                              const short* __restrict__ Vt,
                                              const float* __restrict__ pbias,
                                              short* __restrict__ ctx) {
    __shared__ __align__(16) short Kls[2][64 * TS];     // K tiles [key][d], linear+swizzled (block-shared)
    __shared__ __align__(16) short Vls[2][64 * TS];     // V^T tiles [d][key], linear+swizzled
    __shared__ __align__(16) short Pls[8 * 32 * AST];   // per-wave P [qrow][key]

    const int tid  = threadIdx.x;
    const int lane = tid & 63;
    const int w    = tid >> 6;                    // 0..7
    const int d0   = blockIdx.x;
    const int xcd  = d0 & 7;
    const int idx  = d0 >> 3;                     // 0..127
    const int bh   = xcd * 32 + (idx >> 2);       // same bh -> same XCD
    const int qt   = idx & 3;                     // q-tile of 256 rows
    const int h    = bh & (NH - 1);
    const long long base = (long long)bh * (SEQ * HD);

    const int fr = lane & 15;
    const int fg = lane >> 4;

    const int trow = w * 8 + (lane >> 3);
    const int scol = ((lane & 7) ^ (lane >> 3)) * 8;   // pre-swizzled source col (shorts)
    const int ldso = w * 512;                          // shorts: wave region = rows [w*8, w*8+8)
    const long long kg0 = base + (long long)trow * HD + scol;
    const long long vg0 = base + (long long)trow * SEQ + scol;

    short8 qf[2][2];
#pragma unroll
    for (int mi = 0; mi < 2; ++mi)
#pragma unroll
        for (int ks = 0; ks < 2; ++ks)
            qf[mi][ks] = *(const short8*)(Q + base + (long long)(qt * 256 + w * 32 + mi * 16 + fr) * HD + ks * 32 + fg * 8);

    f32x4 o[2][4] = {};
    f32x4 osum[2] = {};
    short8 vones;
#pragma unroll
    for (int j = 0; j < 8; ++j) vones[j] = (short)0x3F80;  // bf16 1.0

    short* Pw = Pls + w * 32 * AST;
    const float* pbh = pbias + h * PBSTRIDE;
    const int swc = (fr & 7) << 3;   // read-side XOR (shorts)

    gload_lds16(Kg + kg0, Kls[0] + ldso);
    gload_lds16(Vt + vg0, Vls[0] + ldso);
    float pbm[4];
#pragma unroll
    for (int ni = 0; ni < 4; ++ni)
        pbm[ni] = fmaf(pbh[ni * 16 + fr], L2E, -MSUB);
    asm volatile("s_waitcnt vmcnt(0)" ::: "memory");
    __syncthreads();

    int cur = 0;
    for (int kt = 0; kt < 16; ++kt) {
        if (kt < 15) {
            const int nb = cur ^ 1;
            gload_lds16(Kg + kg0 + (long long)((kt + 1) * 64) * HD, Kls[nb] + ldso);
            gload_lds16(Vt + vg0 + (kt + 1) * 64,                   Vls[nb] + ldso);
        }

        f32x4 sc[2][4];
#pragma unroll
        for (int mi = 0; mi < 2; ++mi)
#pragma unroll
            for (int ni = 0; ni < 4; ++ni)
                sc[mi][ni] = (f32x4){pbm[ni], pbm[ni], pbm[ni], pbm[ni]};
        __builtin_amdgcn_s_setprio(1);
#pragma unroll
        for (int ks = 0; ks < 2; ++ks) {
#pragma unroll
            for (int ni = 0; ni < 4; ++ni) {
                short8 kb = *(const short8*)(Kls[cur] + (ni * 16 + fr) * TS + ((ks * 32 + fg * 8) ^ swc));
#pragma unroll
                for (int mi = 0; mi < 2; ++mi)
                    sc[mi][ni] = __builtin_amdgcn_mfma_f32_16x16x32_bf16(qf[mi][ks], kb, sc[mi][ni], 0, 0, 0);
            }
        }
        __builtin_amdgcn_s_setprio(0);

#pragma unroll
        for (int mi = 0; mi < 2; ++mi)
#pragma unroll
            for (int ni = 0; ni < 4; ++ni)
#pragma unroll
                for (int r = 0; r < 4; ++r)
                    Pw[(mi * 16 + fg * 4 + r) * AST + ni * 16 + fr] =
                        f2bf_trunc(EXP2(sc[mi][ni][r]));

        {
            const int nkt = (kt + 1) & 15;
#pragma unroll
            for (int ni = 0; ni < 4; ++ni)
                pbm[ni] = fmaf(pbh[nkt * 64 + ni * 16 + fr], L2E, -MSUB);
        }

        __builtin_amdgcn_s_setprio(1);
#pragma unroll
        for (int ks = 0; ks < 2; ++ks) {
            short8 pa[2];
#pragma unroll
            for (int mi = 0; mi < 2; ++mi)
                pa[mi] = *(const short8*)(Pw + (mi * 16 + fr) * AST + ks * 32 + fg * 8);
            osum[0] = __builtin_amdgcn_mfma_f32_16x16x32_bf16(pa[0], vones, osum[0], 0, 0, 0);
            osum[1] = __builtin_amdgcn_mfma_f32_16x16x32_bf16(pa[1], vones, osum[1], 0, 0, 0);
#pragma unroll
            for (int di = 0; di < 4; ++di) {
                short8 vb = *(const short8*)(Vls[cur] + (di * 16 + fr) * TS + ((ks * 32 + fg * 8) ^ swc));
#pragma unroll
                for (int mi = 0; mi < 2; ++mi)
                    o[mi][di] = __builtin_amdgcn_mfma_f32_16x16x32_bf16(pa[mi], vb, o[mi][di], 0, 0, 0);
            }
        }
        __builtin_amdgcn_s_setprio(0);

        asm volatile("s_waitcnt vmcnt(0)" ::: "memory");
        __syncthreads();
        cur ^= 1;
    }

    const int b = bh >> 4;
#pragma unroll
    for (int mi = 0; mi < 2; ++mi) {
#pragma unroll
        for (int r = 0; r < 4; ++r) {
            float inv = 1.0f / osum[mi][r];
            int srow = qt * 256 + w * 32 + mi * 16 + fg * 4 + r;
#pragma unroll
            for (int di = 0; di < 4; ++di) {
                int d = di * 16 + fr;
                ctx[(long long)(b * SEQ + srow) * HIDN + h * HD + d] = f2bf(o[mi][di][r] * inv);
            }
        }
    }
}

// ---------------- launcher ----------------
extern "C" void kernel_launch(void* const* d_in, const int* in_sizes, int n_in,
                              void* d_out, int out_size, void* d_ws, size_t ws_size,
                              hipStream_t stream) {
    const float* hid  = (const float*)d_in[0];
    const float* Wq   = (const float*)d_in[1];
    const float* bq   = (const float*)d_in[2];
    const float* Wk   = (const float*)d_in[3];
    const float* bk   = (const float*)d_in[4];
    const float* Wv   = (const float*)d_in[5];
    const float* bv   = (const float*)d_in[6];
    const float* Wo   = (const float*)d_in[7];
    const float* bo   = (const float*)d_in[8];
    const float* Wpe  = (const float*)d_in[9];
    const float* bpe  = (const float*)d_in[10];
    const float* pbias = (const float*)d_in[11];

    const long long NE = (long long)BATCH * SEQ * HIDN;  // 16M elements
    const long long WSZ = (long long)HIDN * HIDN;        // 1M elements per weight

    // ws (shorts): hs | v^T | Wcq|Wck|Wcv (contiguous fused [3072][1024]) | Wco | fbias(fp32)
    short* hs   = (short*)d_ws;
    short* vt   = hs + NE;
    short* Wcq  = vt + NE;
    short* Wck  = Wcq + WSZ;
    short* Wcv  = Wck + WSZ;
    short* Wco  = Wcv + WSZ;
    float* fb   = (float*)(Wco + WSZ);
    // d_out: q [0,NE) shorts | k [NE,2NE) shorts — dead before final GEMM overwrites
    short* q    = (short*)d_out;
    short* k    = q + NE;
    short* ctx  = hs;  // alias: hs dead after QKV projection

    posemb_k<<<(int)(NE / 16 / 256), 256, 0, stream>>>(hid, Wpe, bpe, hs);
    convwb_k<<<dim3((int)(WSZ / 4 / 256), 4), 256, 0, stream>>>(Wq, Wk, Wv, Wo, bq, bk, bv,
                                                                Wcq, Wck, Wcv, Wco, fb);

    gemm_qkv<<<3072, 256, 0, stream>>>(hs, Wcq, fb, q, k, vt);

    attn_k<<<1024, 512, 0, stream>>>(q, k, vt, pbias, ctx);

    gemm_out<<<1024, 256, 0, stream>>>(ctx, Wco, bo, (float*)d_out);
}

// Round 22
// 320.780 us; speedup vs baseline: 1.0309x; 1.0309x over previous
//
#include <hip/hip_runtime.h>
#include <hip/hip_bf16.h>
#include <stdint.h>

// Problem constants
#define BATCH 16
#define SEQ   1024
#define HIDN  1024
#define NH    16
#define HD    64
#define PBSTRIDE 1025  // pos_bias last-dim stride (2*512+1)

#define TS  64    // attn K/V tile row stride (shorts) — linear, XOR-swizzled
#define AST 76    // P tile stride (shorts): 38 dw = 6 mod 32 -> conflict-free (r9/r10: 0 conflicts)

// K-projection pre-scale: 0.125 (1/sqrt(D)) * log2(e), folded into Wk/bk in fp32 before bf16 rounding
#define KSCL 0.18033688f
#define L2E  1.44269504f
#define MSUB 11.54156032f   // 8 * log2(e): fixed softmax shift (replaces running max)

// Raw v_exp_f32: args are in [-35,-2] (bounded scores, fixed shift) — no denorm/overflow edge cases.
#if __has_builtin(__builtin_amdgcn_exp2f)
#define EXP2(x) __builtin_amdgcn_exp2f(x)
#else
#define EXP2(x) exp2f(x)
#endif

typedef __attribute__((ext_vector_type(8))) short short8;
typedef __attribute__((ext_vector_type(4))) short short4v;
typedef __attribute__((ext_vector_type(4))) float f32x4;

__device__ __forceinline__ float bf2f(short x) {
    unsigned int u = ((unsigned int)(unsigned short)x) << 16;
    union { unsigned int u; float f; } c; c.u = u; return c.f;
}
__device__ __forceinline__ short f2bf(float f) {
    union { float f; unsigned int u; } c; c.f = f;
    unsigned int r = c.u + 0x7FFFu + ((c.u >> 16) & 1u);  // RNE
    return (short)(r >> 16);
}
// Truncation (1 op). Used ONLY for P: O = sum(P v)/sum(P) uses the same truncated P in
// numerator and denominator, so the ~0.2% downward bias cancels; residual is zero-mean noise.
__device__ __forceinline__ short f2bf_trunc(float f) {
    union { float f; unsigned int u; } c; c.f = f;
    return (short)(c.u >> 16);
}

typedef __attribute__((address_space(1))) void gvoid;
typedef __attribute__((address_space(3))) void svoid;
__device__ __forceinline__ void gload_lds16(const void* g, void* l) {
    __builtin_amdgcn_global_load_lds((gvoid*)g, (svoid*)l, 16, 0, 0);
}

// -------- weight conversion fp32 -> bf16 (all 4 weights, K slot pre-scaled) + fused bias build --------
__global__ void convwb_k(const float* __restrict__ s0, const float* __restrict__ s1,
                         const float* __restrict__ s2, const float* __restrict__ s3,
                         const float* __restrict__ b0, const float* __restrict__ b1,
                         const float* __restrict__ b2,
                         short* __restrict__ d0, short* __restrict__ d1,
                         short* __restrict__ d2, short* __restrict__ d3,
                         float* __restrict__ fbo) {
    const float* src = (blockIdx.y == 0) ? s0 : (blockIdx.y == 1) ? s1 : (blockIdx.y == 2) ? s2 : s3;
    short* dst       = (blockIdx.y == 0) ? d0 : (blockIdx.y == 1) ? d1 : (blockIdx.y == 2) ? d2 : d3;
    const float scl  = (blockIdx.y == 1) ? KSCL : 1.0f;
    int i = (blockIdx.x * 256 + threadIdx.x) * 4;
    float4 f = *(const float4*)(src + i);
    short4v o;
    o[0] = f2bf(f.x * scl); o[1] = f2bf(f.y * scl); o[2] = f2bf(f.z * scl); o[3] = f2bf(f.w * scl);
    *(short4v*)(dst + i) = o;
    // fused q/k/v bias vector [3072], bk slice pre-scaled
    if (blockIdx.y == 0 && blockIdx.x < 12) {
        int i2 = blockIdx.x * 256 + threadIdx.x;  // 0..3071
        const float* s = (i2 < 1024) ? b0 : (i2 < 2048) ? b1 : b2;
        float scl2 = (i2 >= 1024 && i2 < 2048) ? KSCL : 1.0f;
        fbo[i2] = s[i2 & 1023] * scl2;
    }
}

// -------- posemb: hs_bf16 = fp32(hidden) + pos * W_pe + b_pe --------
__global__ void posemb_k(const float* __restrict__ hid, const float* __restrict__ wpe,
                         const float* __restrict__ bpe, short* __restrict__ hs) {
    long long idx = (long long)blockIdx.x * blockDim.x + threadIdx.x;
    long long base = idx * 8;
    int c = (int)(base & (HIDN - 1));
    int s = (int)((base >> 10) & (SEQ - 1));
    float pos = (float)(s - 512) * (1.0f / 512.0f);
    float4 h0 = *(const float4*)(hid + base);
    float4 h1 = *(const float4*)(hid + base + 4);
    float4 w0 = *(const float4*)(wpe + c);
    float4 w1 = *(const float4*)(wpe + c + 4);
    float4 b0 = *(const float4*)(bpe + c);
    float4 b1 = *(const float4*)(bpe + c + 4);
    short8 ov;
    ov[0] = f2bf(h0.x + pos * w0.x + b0.x);
    ov[1] = f2bf(h0.y + pos * w0.y + b0.y);
    ov[2] = f2bf(h0.z + pos * w0.z + b0.z);
    ov[3] = f2bf(h0.w + pos * w0.w + b0.w);
    ov[4] = f2bf(h1.x + pos * w1.x + b1.x);
    ov[5] = f2bf(h1.y + pos * w1.y + b1.y);
    ov[6] = f2bf(h1.z + pos * w1.z + b1.z);
    ov[7] = f2bf(h1.w + pos * w1.w + b1.w);
    *(short8*)(hs + base) = ov;
}

// -------- fused QKV GEMM v3 (r16/r18-verified): BK=64 + swizzle + XCD remap + dbuf pipeline --------
// flat grid 3072: xcd=d&7, tx=(d>>3)/16 (0..23), ty=xcd*16+((d>>3)&15).
// which = tn>>10: 0->q [B,H,S,D], 1->k [B,H,S,D], 2->v^T [B,H,D,S]
__global__ __launch_bounds__(256) void gemm_qkv(const short* __restrict__ A,
                                                const short* __restrict__ W,
                                                const float* __restrict__ fb,
                                                short* __restrict__ q,
                                                short* __restrict__ k,
                                                short* __restrict__ vt) {
    __shared__ __align__(16) short Als[2][128 * 64];
    __shared__ __align__(16) short Bls[2][128 * 64];
    const int tid  = threadIdx.x;
    const int lane = tid & 63;
    const int w    = tid >> 6;
    const int wr   = w >> 1, wc = w & 1;
    const int d0   = blockIdx.x;
    const int xcd  = d0 & 7;
    const int idx  = d0 >> 3;            // 0..383
    const int tx   = idx >> 4;           // 0..23
    const int ty   = xcd * 16 + (idx & 15);
    const int tm   = ty * 128;
    const int tn   = tx * 128;

    f32x4 acc[4][4] = {};

    const int srow = w * 32 + (lane >> 3);
    const int scol = ((lane & 7) ^ (lane >> 3)) * 8;
    const long long a_base = (long long)(tm + srow) * 1024 + scol;
    const long long b_base = (long long)(tn + srow) * 1024 + scol;
    const int ldsw = w * 4096;           // bytes within buffer

    const int fr  = lane & 15;
    const int fg8 = (lane >> 4) * 8;
    const int frx = (lane & 7) * 8;      // read-side XOR (shorts)

#pragma unroll
    for (int c = 0; c < 4; ++c) {
        gload_lds16((const void*)(A + a_base + (long long)c * 8 * 1024), (char*)Als[0] + ldsw + c * 1024);
        gload_lds16((const void*)(W + b_base + (long long)c * 8 * 1024), (char*)Bls[0] + ldsw + c * 1024);
    }
    asm volatile("s_waitcnt vmcnt(0)" ::: "memory");
    __syncthreads();

    int cur = 0;
    for (int k0 = 0; k0 < 1024; k0 += 64) {
        if (k0 + 64 < 1024) {
            const int nb = cur ^ 1;
#pragma unroll
            for (int c = 0; c < 4; ++c) {
                gload_lds16((const void*)(A + a_base + (long long)c * 8 * 1024 + k0 + 64),
                            (char*)Als[nb] + ldsw + c * 1024);
                gload_lds16((const void*)(W + b_base + (long long)c * 8 * 1024 + k0 + 64),
                            (char*)Bls[nb] + ldsw + c * 1024);
            }
        }
#pragma unroll
        for (int ks = 0; ks < 2; ++ks) {
            short8 af[4], bfr[4];
#pragma unroll
            for (int r = 0; r < 4; ++r) {
                af[r]  = *(const short8*)(Als[cur] + (wr * 64 + r * 16 + fr) * 64 + ((ks * 32 + fg8) ^ frx));
                bfr[r] = *(const short8*)(Bls[cur] + (wc * 64 + r * 16 + fr) * 64 + ((ks * 32 + fg8) ^ frx));
            }
#pragma unroll
            for (int mi = 0; mi < 4; ++mi)
#pragma unroll
                for (int ni = 0; ni < 4; ++ni)
                    acc[mi][ni] = __builtin_amdgcn_mfma_f32_16x16x32_bf16(af[mi], bfr[ni], acc[mi][ni], 0, 0, 0);
        }
        __syncthreads();
        cur ^= 1;
    }

    const int which = tn >> 10;  // block-uniform
    const int g4 = (lane >> 4) * 4;
    if (which < 2) {
        short* dst = (which == 0) ? q : k;
#pragma unroll
        for (int ni = 0; ni < 4; ++ni) {
            int col = tn + wc * 64 + ni * 16 + fr;
            int cc  = col & 1023;
            int h   = cc >> 6, d = cc & 63;
            float bv = fb[col];
#pragma unroll
            for (int mi = 0; mi < 4; ++mi) {
#pragma unroll
                for (int r = 0; r < 4; ++r) {
                    int row = tm + wr * 64 + mi * 16 + g4 + r;
                    int b = row >> 10, s = row & 1023;
                    dst[(((long long)(b * NH + h) * SEQ + s) << 6) + d] = f2bf(acc[mi][ni][r] + bv);
                }
            }
        }
    } else {
        // v^T: rows (s) consecutive over r -> vectorized short4 stores (r15-verified)
#pragma unroll
        for (int ni = 0; ni < 4; ++ni) {
            int col = tn + wc * 64 + ni * 16 + fr;
            int cc  = col & 1023;
            int h   = cc >> 6, d = cc & 63;
            float bv = fb[col];
#pragma unroll
            for (int mi = 0; mi < 4; ++mi) {
                int row0 = tm + wr * 64 + mi * 16 + g4;
                int b = row0 >> 10, s0 = row0 & 1023;
                short4v o4;
#pragma unroll
                for (int r = 0; r < 4; ++r) o4[r] = f2bf(acc[mi][ni][r] + bv);
                *(short4v*)(vt + ((long long)(b * NH + h) * HD + d) * SEQ + s0) = o4;
            }
        }
    }
}

// -------- out-proj GEMM v3 (r15-verified): BK=64 + swizzle + XCD remap + dbuf; fp32 out --------
__global__ __launch_bounds__(256) void gemm_out(const short* __restrict__ A,
                                                const short* __restrict__ W,
                                                const float* __restrict__ bias,
                                                float* __restrict__ Cout) {
    __shared__ __align__(16) short Als[2][128 * 64];
    __shared__ __align__(16) short Bls[2][128 * 64];
    const int tid  = threadIdx.x;
    const int lane = tid & 63;
    const int w    = tid >> 6;
    const int wr   = w >> 1, wc = w & 1;
    const int d0   = blockIdx.x;
    const int xcd  = d0 & 7;
    const int idx  = d0 >> 3;            // 0..127
    const int tx   = idx >> 4;           // 0..7
    const int ty   = xcd * 16 + (idx & 15);
    const int tm   = ty * 128;
    const int tn   = tx * 128;

    f32x4 acc[4][4] = {};

    const int srow = w * 32 + (lane >> 3);
    const int scol = ((lane & 7) ^ (lane >> 3)) * 8;
    const long long a_base = (long long)(tm + srow) * 1024 + scol;
    const long long b_base = (long long)(tn + srow) * 1024 + scol;
    const int ldsw = w * 4096;

    const int fr  = lane & 15;
    const int fg8 = (lane >> 4) * 8;
    const int frx = (lane & 7) * 8;

#pragma unroll
    for (int c = 0; c < 4; ++c) {
        gload_lds16((const void*)(A + a_base + (long long)c * 8 * 1024), (char*)Als[0] + ldsw + c * 1024);
        gload_lds16((const void*)(W + b_base + (long long)c * 8 * 1024), (char*)Bls[0] + ldsw + c * 1024);
    }
    asm volatile("s_waitcnt vmcnt(0)" ::: "memory");
    __syncthreads();

    int cur = 0;
    for (int k0 = 0; k0 < 1024; k0 += 64) {
        if (k0 + 64 < 1024) {
            const int nb = cur ^ 1;
#pragma unroll
            for (int c = 0; c < 4; ++c) {
                gload_lds16((const void*)(A + a_base + (long long)c * 8 * 1024 + k0 + 64),
                            (char*)Als[nb] + ldsw + c * 1024);
                gload_lds16((const void*)(W + b_base + (long long)c * 8 * 1024 + k0 + 64),
                            (char*)Bls[nb] + ldsw + c * 1024);
            }
        }
#pragma unroll
        for (int ks = 0; ks < 2; ++ks) {
            short8 af[4], bfr[4];
#pragma unroll
            for (int r = 0; r < 4; ++r) {
                af[r]  = *(const short8*)(Als[cur] + (wr * 64 + r * 16 + fr) * 64 + ((ks * 32 + fg8) ^ frx));
                bfr[r] = *(const short8*)(Bls[cur] + (wc * 64 + r * 16 + fr) * 64 + ((ks * 32 + fg8) ^ frx));
            }
#pragma unroll
            for (int mi = 0; mi < 4; ++mi)
#pragma unroll
                for (int ni = 0; ni < 4; ++ni)
                    acc[mi][ni] = __builtin_amdgcn_mfma_f32_16x16x32_bf16(af[mi], bfr[ni], acc[mi][ni], 0, 0, 0);
        }
        __syncthreads();
        cur ^= 1;
    }

    const int g4 = (lane >> 4) * 4;
#pragma unroll
    for (int ni = 0; ni < 4; ++ni) {
        int col = tn + wc * 64 + ni * 16 + fr;
        float bv = bias[col];
#pragma unroll
        for (int mi = 0; mi < 4; ++mi)
#pragma unroll
            for (int r = 0; r < 4; ++r) {
                int row = tm + wr * 64 + mi * 16 + g4 + r;
                Cout[(long long)row * 1024 + col] = acc[mi][ni][r] + bv;
            }
    }
}

// -------- attention v11 (r16-verified): 8-wave, dbuf gload_lds, XCD remap, C-init bias, trunc P --------
// grid 1024: xcd=d&7, idx=d>>3; bh=xcd*32+(idx>>2), qt=idx&3 (bh XCD-affine, bijective).
__global__ __launch_bounds__(512) void attn_k(const short* __restrict__ Q,
                                              const short* __restrict__ Kg,
                                              const short* __restrict__ Vt,
                                              const float* __restrict__ pbias,
                                              short* __restrict__ ctx) {
    __shared__ __align__(16) short Kls[2][64 * TS];     // K tiles [key][d], linear+swizzled (block-shared)
    __shared__ __align__(16) short Vls[2][64 * TS];     // V^T tiles [d][key], linear+swizzled
    __shared__ __align__(16) short Pls[8 * 32 * AST];   // per-wave P [qrow][key]

    const int tid  = threadIdx.x;
    const int lane = tid & 63;
    const int w    = tid >> 6;                    // 0..7
    const int d0   = blockIdx.x;
    const int xcd  = d0 & 7;
    const int idx  = d0 >> 3;                     // 0..127
    const int bh   = xcd * 32 + (idx >> 2);       // same bh -> same XCD
    const int qt   = idx & 3;                     // q-tile of 256 rows
    const int h    = bh & (NH - 1);
    const long long base = (long long)bh * (SEQ * HD);

    const int fr = lane & 15;
    const int fg = lane >> 4;

    const int trow = w * 8 + (lane >> 3);
    const int scol = ((lane & 7) ^ (lane >> 3)) * 8;   // pre-swizzled source col (shorts)
    const int ldso = w * 512;                          // shorts: wave region = rows [w*8, w*8+8)
    const long long kg0 = base + (long long)trow * HD + scol;
    const long long vg0 = base + (long long)trow * SEQ + scol;

    short8 qf[2][2];
#pragma unroll
    for (int mi = 0; mi < 2; ++mi)
#pragma unroll
        for (int ks = 0; ks < 2; ++ks)
            qf[mi][ks] = *(const short8*)(Q + base + (long long)(qt * 256 + w * 32 + mi * 16 + fr) * HD + ks * 32 + fg * 8);

    f32x4 o[2][4] = {};
    f32x4 osum[2] = {};
    short8 vones;
#pragma unroll
    for (int j = 0; j < 8; ++j) vones[j] = (short)0x3F80;  // bf16 1.0

    short* Pw = Pls + w * 32 * AST;
    const float* pbh = pbias + h * PBSTRIDE;
    const int swc = (fr & 7) << 3;   // read-side XOR (shorts)

    gload_lds16(Kg + kg0, Kls[0] + ldso);
    gload_lds16(Vt + vg0, Vls[0] + ldso);
    float pbm[4];
#pragma unroll
    for (int ni = 0; ni < 4; ++ni)
        pbm[ni] = fmaf(pbh[ni * 16 + fr], L2E, -MSUB);
    asm volatile("s_waitcnt vmcnt(0)" ::: "memory");
    __syncthreads();

    int cur = 0;
    for (int kt = 0; kt < 16; ++kt) {
        if (kt < 15) {
            const int nb = cur ^ 1;
            gload_lds16(Kg + kg0 + (long long)((kt + 1) * 64) * HD, Kls[nb] + ldso);
            gload_lds16(Vt + vg0 + (kt + 1) * 64,                   Vls[nb] + ldso);
        }

        f32x4 sc[2][4];
#pragma unroll
        for (int mi = 0; mi < 2; ++mi)
#pragma unroll
            for (int ni = 0; ni < 4; ++ni)
                sc[mi][ni] = (f32x4){pbm[ni], pbm[ni], pbm[ni], pbm[ni]};
        __builtin_amdgcn_s_setprio(1);
#pragma unroll
        for (int ks = 0; ks < 2; ++ks) {
#pragma unroll
            for (int ni = 0; ni < 4; ++ni) {
                short8 kb = *(const short8*)(Kls[cur] + (ni * 16 + fr) * TS + ((ks * 32 + fg * 8) ^ swc));
#pragma unroll
                for (int mi = 0; mi < 2; ++mi)
                    sc[mi][ni] = __builtin_amdgcn_mfma_f32_16x16x32_bf16(qf[mi][ks], kb, sc[mi][ni], 0, 0, 0);
            }
        }
        __builtin_amdgcn_s_setprio(0);

#pragma unroll
        for (int mi = 0; mi < 2; ++mi)
#pragma unroll
            for (int ni = 0; ni < 4; ++ni)
#pragma unroll
                for (int r = 0; r < 4; ++r)
                    Pw[(mi * 16 + fg * 4 + r) * AST + ni * 16 + fr] =
                        f2bf_trunc(EXP2(sc[mi][ni][r]));

        {
            const int nkt = (kt + 1) & 15;
#pragma unroll
            for (int ni = 0; ni < 4; ++ni)
                pbm[ni] = fmaf(pbh[nkt * 64 + ni * 16 + fr], L2E, -MSUB);
        }

        __builtin_amdgcn_s_setprio(1);
#pragma unroll
        for (int ks = 0; ks < 2; ++ks) {
            short8 pa[2];
#pragma unroll
            for (int mi = 0; mi < 2; ++mi)
                pa[mi] = *(const short8*)(Pw + (mi * 16 + fr) * AST + ks * 32 + fg * 8);
            osum[0] = __builtin_amdgcn_mfma_f32_16x16x32_bf16(pa[0], vones, osum[0], 0, 0, 0);
            osum[1] = __builtin_amdgcn_mfma_f32_16x16x32_bf16(pa[1], vones, osum[1], 0, 0, 0);
#pragma unroll
            for (int di = 0; di < 4; ++di) {
                short8 vb = *(const short8*)(Vls[cur] + (di * 16 + fr) * TS + ((ks * 32 + fg * 8) ^ swc));
#pragma unroll
                for (int mi = 0; mi < 2; ++mi)
                    o[mi][di] = __builtin_amdgcn_mfma_f32_16x16x32_bf16(pa[mi], vb, o[mi][di], 0, 0, 0);
            }
        }
        __builtin_amdgcn_s_setprio(0);

        asm volatile("s_waitcnt vmcnt(0)" ::: "memory");
        __syncthreads();
        cur ^= 1;
    }

    const int b = bh >> 4;
#pragma unroll
    for (int mi = 0; mi < 2; ++mi) {
#pragma unroll
        for (int r = 0; r < 4; ++r) {
            float inv = 1.0f / osum[mi][r];
            int srow = qt * 256 + w * 32 + mi * 16 + fg * 4 + r;
#pragma unroll
            for (int di = 0; di < 4; ++di) {
                int d = di * 16 + fr;
                ctx[(long long)(b * SEQ + srow) * HIDN + h * HD + d] = f2bf(o[mi][di][r] * inv);
            }
        }
    }
}

// ---------------- launcher ----------------
extern "C" void kernel_launch(void* const* d_in, const int* in_sizes, int n_in,
                              void* d_out, int out_size, void* d_ws, size_t ws_size,
                              hipStream_t stream) {
    const float* hid  = (const float*)d_in[0];
    const float* Wq   = (const float*)d_in[1];
    const float* bq   = (const float*)d_in[2];
    const float* Wk   = (const float*)d_in[3];
    const float* bk   = (const float*)d_in[4];
    const float* Wv   = (const float*)d_in[5];
    const float* bv   = (const float*)d_in[6];
    const float* Wo   = (const float*)d_in[7];
    const float* bo   = (const float*)d_in[8];
    const float* Wpe  = (const float*)d_in[9];
    const float* bpe  = (const float*)d_in[10];
    const float* pbias = (const float*)d_in[11];

    const long long NE = (long long)BATCH * SEQ * HIDN;  // 16M elements
    const long long WSZ = (long long)HIDN * HIDN;        // 1M elements per weight

    // ws (shorts): hs | v^T | Wcq|Wck|Wcv (contiguous fused [3072][1024]) | Wco | fbias(fp32)
    short* hs   = (short*)d_ws;
    short* vt   = hs + NE;
    short* Wcq  = vt + NE;
    short* Wck  = Wcq + WSZ;
    short* Wcv  = Wck + WSZ;
    short* Wco  = Wcv + WSZ;
    float* fb   = (float*)(Wco + WSZ);
    // d_out: q [0,NE) shorts | k [NE,2NE) shorts — dead before final GEMM overwrites
    short* q    = (short*)d_out;
    short* k    = q + NE;
    short* ctx  = hs;  // alias: hs dead after QKV projection

    posemb_k<<<(int)(NE / 8 / 256), 256, 0, stream>>>(hid, Wpe, bpe, hs);
    convwb_k<<<dim3((int)(WSZ / 4 / 256), 4), 256, 0, stream>>>(Wq, Wk, Wv, Wo, bq, bk, bv,
                                                                Wcq, Wck, Wcv, Wco, fb);

    gemm_qkv<<<3072, 256, 0, stream>>>(hs, Wcq, fb, q, k, vt);

    attn_k<<<1024, 512, 0, stream>>>(q, k, vt, pbias, ctx);

    gemm_out<<<1024, 256, 0, stream>>>(ctx, Wco, bo, (float*)d_out);
}